// Round 14
// baseline (84.827 us; speedup 1.0000x reference)
//
#include <hip/hip_runtime.h>
#include <cmath>

typedef __attribute__((ext_vector_type(8))) short short8;
typedef __attribute__((ext_vector_type(4))) float f32x4;

#define ALPHA_ 0.2f
#define NEGINF (-9.0e15f)

__device__ __forceinline__ ushort f2b(float f) {
    union { float f; unsigned u; } v; v.f = f;
    unsigned r = v.u + 0x7fffu + ((v.u >> 16) & 1u);
    return (ushort)(r >> 16);
}

// ---------------------------------------------------------------------------
// prep (grid 200 x 256)  [R6-verified, unchanged]
// ---------------------------------------------------------------------------
__global__ __launch_bounds__(256) void prep_kernel(
    const int* __restrict__ adj, const float* __restrict__ W10,
    const float* __restrict__ W11, const float* __restrict__ W2,
    const float* __restrict__ a10, const float* __restrict__ a11,
    unsigned* __restrict__ adjb, ushort* __restrict__ WT1,
    ushort* __restrict__ WT2, float* __restrict__ AC1,
    ushort* __restrict__ HT)
{
    const int bx = blockIdx.x, tid = threadIdx.x;
    if (tid < 8) {
        unsigned mask = 0;
        for (int u = 0; u < 32; ++u) {
            const int j = tid * 32 + u;
            if (j < 200 && adj[bx * 200 + j] > 0) mask |= (1u << u);
        }
        adjb[bx * 8 + tid] = mask;
    }
    const int gidx = bx * 256 + tid;                 // 0..51199
    if (gidx < 64 * 320) {
        const int n = gidx / 320, k = gidx % 320;
        WT1[gidx] = f2b(n < 32 ? W10[k * 32 + n] : W11[k * 32 + (n - 32)]);
    }
    if (gidx < 64 * 64) {
        const int n = gidx >> 6, k = gidx & 63;
        WT2[gidx] = f2b(W2[k * 64 + n]);
    }
    if (gidx < 256) {                                // AC1
        const int q = gidx >> 6, f = gidx & 63;
        float v = 0.f;
        if (q == 0 && f < 32)  v = a10[f];
        if (q == 1 && f < 32)  v = a10[32 + f];
        if (q == 2 && f >= 32) v = a11[f - 32];
        if (q == 3 && f >= 32) v = a11[f];           // a11[32 + (f-32)]
        AC1[gidx] = v;
    }
    if (gidx < 256 * 64 * 3) {                       // HT pad zero (3 x uint4 per row)
        const int c = gidx % 3, bf = gidx / 3;
        uint4 z{0, 0, 0, 0};
        *(uint4*)&HT[(size_t)bf * 224 + 200 + c * 8] = z;
    }
}

// ---------------------------------------------------------------------------
// gemm + fused src/dst dots.  R14: W^T LDS tile REMOVED — B-fragments read
// directly from the L2-resident WT table (40 KB / 8 KB, shared by all 800
// blocks; identical bytes).  LDS 43 KB -> ~1 KB => occupancy cap lifts from
// 3 blocks/CU to wave-slot limit, hiding the scattered x-load latency.
// ---------------------------------------------------------------------------
template<int K, int LDX, int NSD>
__global__ __launch_bounds__(256) void gemm_mfma(const float* __restrict__ X,
                                                 const ushort* __restrict__ WT,
                                                 const float* __restrict__ AC,
                                                 ushort* __restrict__ HT,
                                                 float* __restrict__ SD)
{
    __shared__ __attribute__((aligned(16))) float acl[NSD * 64];
    const int tid = threadIdx.x;
    if (tid < NSD * 64) acl[tid] = AC[tid];
    __syncthreads();

    const int lane = tid & 63, w = tid >> 6;
    const int m = lane & 15, g = lane >> 4;
    const int ko = g * 8;
    const size_t row = (size_t)blockIdx.x * 64 + w * 16 + m;
    const ushort* wb = WT + m * K + ko;              // per-lane W base (L2-hot)

    f32x4 acc[4] = {{0,0,0,0},{0,0,0,0},{0,0,0,0},{0,0,0,0}};
    #pragma unroll
    for (int k0 = 0; k0 < K; k0 += 32) {
        const float4 x0 = *(const float4*)&X[row * LDX + k0 + ko];
        const float4 x1 = *(const float4*)&X[row * LDX + k0 + ko + 4];
        short8 a;
        a[0] = (short)f2b(x0.x); a[1] = (short)f2b(x0.y);
        a[2] = (short)f2b(x0.z); a[3] = (short)f2b(x0.w);
        a[4] = (short)f2b(x1.x); a[5] = (short)f2b(x1.y);
        a[6] = (short)f2b(x1.z); a[7] = (short)f2b(x1.w);
        #pragma unroll
        for (int nt = 0; nt < 4; ++nt) {
            const short8 bfr = *(const short8*)&wb[nt * 16 * K + k0];
            acc[nt] = __builtin_amdgcn_mfma_f32_16x16x32_bf16(a, bfr, acc[nt], 0, 0, 0);
        }
    }

    const unsigned rb = (unsigned)blockIdx.x * 64 + w * 16 + g * 4;  // 4 | 200
    const unsigned bt = rb / 200u;
    const unsigned ir = rb - bt * 200u;
    #pragma unroll
    for (int nt = 0; nt < 4; ++nt) {
        uint2 pk;
        pk.x = (unsigned)f2b(acc[nt][0]) | ((unsigned)f2b(acc[nt][1]) << 16);
        pk.y = (unsigned)f2b(acc[nt][2]) | ((unsigned)f2b(acc[nt][3]) << 16);
        *(uint2*)&HT[((size_t)bt * 64 + nt * 16 + m) * 224 + ir] = pk;
    }

    float sdv[NSD][4];
    #pragma unroll
    for (int q = 0; q < NSD; ++q)
        #pragma unroll
        for (int r = 0; r < 4; ++r) {
            float s = 0.f;
            #pragma unroll
            for (int nt = 0; nt < 4; ++nt) s += acc[nt][r] * acl[q * 64 + nt * 16 + m];
            sdv[q][r] = s;
        }
    #pragma unroll
    for (int q = 0; q < NSD; ++q)
        #pragma unroll
        for (int r = 0; r < 4; ++r) {
            float s = sdv[q][r];
            s += __shfl_xor(s, 1, 64); s += __shfl_xor(s, 2, 64);
            s += __shfl_xor(s, 4, 64); s += __shfl_xor(s, 8, 64);
            sdv[q][r] = s;
        }
    if (m == 0) {
        #pragma unroll
        for (int r = 0; r < 4; ++r) {
            if (NSD == 4) {
                float4 o; o.x = sdv[0][r]; o.y = sdv[1][r];
                o.z = sdv[2][r]; o.w = sdv[3][r];
                *(float4*)&SD[(size_t)(rb + r) * 4] = o;
            } else {
                float2 o; o.x = sdv[0][r]; o.y = sdv[1][r];
                *(float2*)&SD[(size_t)(rb + r) * 2] = o;
            }
        }
    }
}

// ---------------------------------------------------------------------------
// Fused GAT attention [R13-verified, unchanged]: block-local adjl/src_l,
// LDS hT staging, single-pass no-max softmax, ks-outer PV, swizzle, setprio.
// MODE 0: bx = ((b*2+head)*2+sub), sub {0,1}: tiles 0..6 / 7..12. F=32.
// MODE 1: bx = b*4+sub, sub {0..3}: tiles {0-3,4-6,7-9,10-12}. F=64.
// ---------------------------------------------------------------------------
template<int F, int MODE>
__global__ __launch_bounds__(256) void attn_mfma(const ushort* __restrict__ HT,
                                                 const unsigned* __restrict__ adjb,
                                                 const float* __restrict__ sd,
                                                 float* __restrict__ out)
{
    constexpr int NROW = (MODE == 0) ? 112 : 64;     // max rows per block
    __shared__ __attribute__((aligned(16))) ushort hT[F][232];
    __shared__ __attribute__((aligned(16))) float src_l[NROW];
    __shared__ __attribute__((aligned(16))) float dst_l[224];
    __shared__ unsigned adjl[NROW][9];   // pad 9 -> conflict-free row reads

    const int tid = threadIdx.x;
    const int lane = tid & 63, w = tid >> 6;
    // XCD swizzle (1024 = 8 x 128, bijective relabeling)
    const int bx = ((blockIdx.x & 7) << 7) | (blockIdx.x >> 3);
    int b, hoff, outc0, head, tA, tB;
    if (MODE == 0) {
        b = bx >> 2; head = (bx >> 1) & 1; const int sub = bx & 1;
        hoff = head * 32; outc0 = head * 32;
        tA = sub ? 7 : 0; tB = sub ? 13 : 7;
    } else {
        b = bx >> 2; head = 0; const int sub = bx & 3;
        hoff = 0; outc0 = 64;
        tA = (sub == 0) ? 0 : 4 + (sub - 1) * 3;
        tB = (sub == 0) ? 4 : tA + 3;
    }
    const int r0 = tA * 16;                          // first row of this block

    // stage hT (coalesced short8)
    const ushort* hg = HT + ((size_t)b * 64 + hoff) * 224;
    for (int idx = tid; idx < F * 28; idx += 256) {
        const int f = idx / 28, c = idx % 28;
        *(short8*)&hT[f][c * 8] = *(const short8*)&hg[(size_t)f * 224 + c * 8];
    }
    // stage adj bitmasks for OWN rows only (rows >= 200 -> 0)
    for (int idx = tid; idx < NROW * 8; idx += 256) {
        const int il = idx >> 3, c = idx & 7;
        const int i = r0 + il;
        adjl[il][c] = (i < 200) ? adjb[i * 8 + c] : 0u;
    }
    // stage dst (all cols) / src (own rows only)
    if (tid < 224) {
        float s = 0.f, d = 0.f;
        if (tid < 200) {
            if (MODE == 0) {
                const float4 q4 = *(const float4*)&sd[(size_t)(b * 200 + tid) * 4];
                s = head ? q4.z : q4.x;
                d = head ? q4.w : q4.y;
            } else {
                const float2 q2 = *(const float2*)&sd[(size_t)(b * 200 + tid) * 2];
                s = q2.x; d = q2.y;
            }
        }
        dst_l[tid] = d;
        const int local = tid - r0;
        if (local >= 0 && local < NROW) src_l[local] = s;
    }
    __syncthreads();

    const int m = lane & 15, g = lane >> 4;

    for (int t = tA + w; t < tB; t += 4) {
        const int i0 = t * 16;
        const int il = i0 - r0 + m;                  // local row index
        const float si = src_l[il];

        f32x4 acc[F / 16];
        #pragma unroll
        for (int nt = 0; nt < F / 16; ++nt) acc[nt] = f32x4{0, 0, 0, 0};
        float sum = 0.f;

        #pragma unroll
        for (int ks = 0; ks < 7; ++ks) {
            const unsigned bits = (adjl[il][ks] >> (g * 8)) & 0xffu;
            const float4 d0 = *(const float4*)&dst_l[ks * 32 + g * 8];
            const float4 d1 = *(const float4*)&dst_l[ks * 32 + g * 8 + 4];
            const float dvv[8] = {d0.x, d0.y, d0.z, d0.w, d1.x, d1.y, d1.z, d1.w};
            short8 af;
            #pragma unroll
            for (int u = 0; u < 8; ++u) {
                float v = si + dvv[u];
                v = fmaxf(v, ALPHA_ * v);                       // leaky-relu
                const float e = ((bits >> u) & 1u) ? v : NEGINF;
                const float p = __expf(fminf(e, 80.f));
                sum += p;
                af[u] = (short)f2b(p);
            }
            __builtin_amdgcn_s_setprio(1);
            #pragma unroll
            for (int nt = 0; nt < F / 16; ++nt) {
                const short8 bf = *(const short8*)&hT[nt * 16 + m][ks * 32 + g * 8];
                acc[nt] = __builtin_amdgcn_mfma_f32_16x16x32_bf16(af, bf, acc[nt], 0, 0, 0);
            }
            __builtin_amdgcn_s_setprio(0);
        }

        sum += __shfl_xor(sum, 16, 64);
        sum += __shfl_xor(sum, 32, 64);
        const float inv = 1.f / sum;           // inverse for row i0+m
        float invr[4];
        #pragma unroll
        for (int r = 0; r < 4; ++r) invr[r] = __shfl(inv, g * 4 + r, 64);

        #pragma unroll
        for (int nt = 0; nt < F / 16; ++nt) {
            #pragma unroll
            for (int r = 0; r < 4; ++r) {
                const int ii = i0 + g * 4 + r;
                if (ii < 200) {
                    float vv = acc[nt][r] * invr[r];
                    vv = (vv > 0.f) ? vv : expm1f(vv);          // accurate ELU
                    out[((size_t)b * 200 + ii) * 128 + outc0 + nt * 16 + m] = vv;
                }
            }
        }
    }
}

extern "C" void kernel_launch(void* const* d_in, const int* in_sizes, int n_in,
                              void* d_out, int out_size, void* d_ws, size_t ws_size,
                              hipStream_t stream)
{
    const float* x   = (const float*)d_in[0];
    const int*   adj = (const int*)  d_in[1];
    const float* W10 = (const float*)d_in[2];
    const float* a10 = (const float*)d_in[3];
    const float* W11 = (const float*)d_in[4];
    const float* a11 = (const float*)d_in[5];
    const float* W2  = (const float*)d_in[6];
    const float* a2  = (const float*)d_in[7];
    float* out = (float*)d_out;

    char* ws = (char*)d_ws;
    ushort*   HT   = (ushort*)  ws;                  // 7,340,032 B
    ushort*   WT1  = (ushort*) (ws + 7340032);       //    40,960 B
    ushort*   WT2  = (ushort*) (ws + 7380992);       //     8,192 B
    unsigned* adjb = (unsigned*)(ws + 7389184);      //     6,400 B
    float*    AC1  = (float*)  (ws + 7395584);       //     1,024 B
    float*    sd1  = (float*)  (ws + 7396608);       //   819,200 B
    float*    sd2  = (float*)  (ws + 8215808);       //   409,600 B  (8.63 MB)

    prep_kernel<<<200, 256, 0, stream>>>(adj, W10, W11, W2, a10, a11,
                                         adjb, WT1, WT2, AC1, HT);
    gemm_mfma<320, 320, 4><<<800, 256, 0, stream>>>(x, WT1, AC1, HT, sd1);
    attn_mfma<32, 0><<<1024, 256, 0, stream>>>(HT, adjb, sd1, out);
    gemm_mfma<64, 128, 2><<<800, 256, 0, stream>>>(out, WT2, a2, HT, sd2);
    attn_mfma<64, 1><<<1024, 256, 0, stream>>>(HT, adjb, sd2, out);
}

// Round 15
// 73.821 us; speedup vs baseline: 1.1491x; 1.1491x over previous
//
#include <hip/hip_runtime.h>
#include <cmath>

typedef __attribute__((ext_vector_type(8))) short short8;
typedef __attribute__((ext_vector_type(4))) float f32x4;

#define ALPHA_ 0.2f
#define NEGINF (-9.0e15f)

__device__ __forceinline__ ushort f2b(float f) {
    union { float f; unsigned u; } v; v.f = f;
    unsigned r = v.u + 0x7fffu + ((v.u >> 16) & 1u);
    return (ushort)(r >> 16);
}

// ---------------------------------------------------------------------------
// prep (grid 200 x 256)  [R6-verified, unchanged]
// ---------------------------------------------------------------------------
__global__ __launch_bounds__(256) void prep_kernel(
    const int* __restrict__ adj, const float* __restrict__ W10,
    const float* __restrict__ W11, const float* __restrict__ W2,
    const float* __restrict__ a10, const float* __restrict__ a11,
    unsigned* __restrict__ adjb, ushort* __restrict__ WT1,
    ushort* __restrict__ WT2, float* __restrict__ AC1,
    ushort* __restrict__ HT)
{
    const int bx = blockIdx.x, tid = threadIdx.x;
    if (tid < 8) {
        unsigned mask = 0;
        for (int u = 0; u < 32; ++u) {
            const int j = tid * 32 + u;
            if (j < 200 && adj[bx * 200 + j] > 0) mask |= (1u << u);
        }
        adjb[bx * 8 + tid] = mask;
    }
    const int gidx = bx * 256 + tid;                 // 0..51199
    if (gidx < 64 * 320) {
        const int n = gidx / 320, k = gidx % 320;
        WT1[gidx] = f2b(n < 32 ? W10[k * 32 + n] : W11[k * 32 + (n - 32)]);
    }
    if (gidx < 64 * 64) {
        const int n = gidx >> 6, k = gidx & 63;
        WT2[gidx] = f2b(W2[k * 64 + n]);
    }
    if (gidx < 256) {                                // AC1
        const int q = gidx >> 6, f = gidx & 63;
        float v = 0.f;
        if (q == 0 && f < 32)  v = a10[f];
        if (q == 1 && f < 32)  v = a10[32 + f];
        if (q == 2 && f >= 32) v = a11[f - 32];
        if (q == 3 && f >= 32) v = a11[f];           // a11[32 + (f-32)]
        AC1[gidx] = v;
    }
    if (gidx < 256 * 64 * 3) {                       // HT pad zero (3 x uint4 per row)
        const int c = gidx % 3, bf = gidx / 3;
        uint4 z{0, 0, 0, 0};
        *(uint4*)&HT[(size_t)bf * 224 + 200 + c * 8] = z;
    }
}

// ---------------------------------------------------------------------------
// gemm + fused src/dst dots.  R15: W^T LDS tile RESTORED (R13 structure);
// new: ALL x-loads hoisted into registers (xr[K/32][2], static-indexed)
// and issued BEFORE the W staging loop — the HBM latency hides under
// staging + barrier, and the compute loop runs load-free from registers.
// ---------------------------------------------------------------------------
template<int K, int LDX, int NSD>
__global__ __launch_bounds__(256) void gemm_mfma(const float* __restrict__ X,
                                                 const ushort* __restrict__ WT,
                                                 const float* __restrict__ AC,
                                                 ushort* __restrict__ HT,
                                                 float* __restrict__ SD)
{
    constexpr int KP = K + 8;
    constexpr int NK = K / 32;
    __shared__ __attribute__((aligned(16))) ushort wt_lds[64][KP];
    __shared__ __attribute__((aligned(16))) float acl[NSD * 64];
    const int tid = threadIdx.x;
    const int lane = tid & 63, w = tid >> 6;
    const int m = lane & 15, g = lane >> 4;
    const int ko = g * 8;
    const size_t row = (size_t)blockIdx.x * 64 + w * 16 + m;

    // ---- issue ALL x loads first (20 outstanding for K=320)
    float4 xr[NK][2];
    #pragma unroll
    for (int kk = 0; kk < NK; ++kk) {
        xr[kk][0] = *(const float4*)&X[row * LDX + kk * 32 + ko];
        xr[kk][1] = *(const float4*)&X[row * LDX + kk * 32 + ko + 4];
    }

    // ---- stage W^T into LDS (overlaps with x loads in flight)
    constexpr int CH = 64 * (K / 8);
    for (int c = tid; c < CH; c += 256) {
        int n = c / (K / 8), kc = (c % (K / 8)) * 8;
        *(short8*)&wt_lds[n][kc] = *(const short8*)&WT[n * K + kc];
    }
    if (tid < NSD * 64) acl[tid] = AC[tid];
    __syncthreads();

    // ---- compute: register-resident x, LDS-resident W
    f32x4 acc[4] = {{0,0,0,0},{0,0,0,0},{0,0,0,0},{0,0,0,0}};
    #pragma unroll
    for (int kk = 0; kk < NK; ++kk) {
        const float4 x0 = xr[kk][0];
        const float4 x1 = xr[kk][1];
        short8 a;
        a[0] = (short)f2b(x0.x); a[1] = (short)f2b(x0.y);
        a[2] = (short)f2b(x0.z); a[3] = (short)f2b(x0.w);
        a[4] = (short)f2b(x1.x); a[5] = (short)f2b(x1.y);
        a[6] = (short)f2b(x1.z); a[7] = (short)f2b(x1.w);
        #pragma unroll
        for (int nt = 0; nt < 4; ++nt) {
            const short8 bfr = *(const short8*)&wt_lds[nt * 16 + m][kk * 32 + ko];
            acc[nt] = __builtin_amdgcn_mfma_f32_16x16x32_bf16(a, bfr, acc[nt], 0, 0, 0);
        }
    }

    const unsigned rb = (unsigned)blockIdx.x * 64 + w * 16 + g * 4;  // 4 | 200
    const unsigned bt = rb / 200u;
    const unsigned ir = rb - bt * 200u;
    #pragma unroll
    for (int nt = 0; nt < 4; ++nt) {
        uint2 pk;
        pk.x = (unsigned)f2b(acc[nt][0]) | ((unsigned)f2b(acc[nt][1]) << 16);
        pk.y = (unsigned)f2b(acc[nt][2]) | ((unsigned)f2b(acc[nt][3]) << 16);
        *(uint2*)&HT[((size_t)bt * 64 + nt * 16 + m) * 224 + ir] = pk;
    }

    float sdv[NSD][4];
    #pragma unroll
    for (int q = 0; q < NSD; ++q)
        #pragma unroll
        for (int r = 0; r < 4; ++r) {
            float s = 0.f;
            #pragma unroll
            for (int nt = 0; nt < 4; ++nt) s += acc[nt][r] * acl[q * 64 + nt * 16 + m];
            sdv[q][r] = s;
        }
    #pragma unroll
    for (int q = 0; q < NSD; ++q)
        #pragma unroll
        for (int r = 0; r < 4; ++r) {
            float s = sdv[q][r];
            s += __shfl_xor(s, 1, 64); s += __shfl_xor(s, 2, 64);
            s += __shfl_xor(s, 4, 64); s += __shfl_xor(s, 8, 64);
            sdv[q][r] = s;
        }
    if (m == 0) {
        #pragma unroll
        for (int r = 0; r < 4; ++r) {
            if (NSD == 4) {
                float4 o; o.x = sdv[0][r]; o.y = sdv[1][r];
                o.z = sdv[2][r]; o.w = sdv[3][r];
                *(float4*)&SD[(size_t)(rb + r) * 4] = o;
            } else {
                float2 o; o.x = sdv[0][r]; o.y = sdv[1][r];
                *(float2*)&SD[(size_t)(rb + r) * 2] = o;
            }
        }
    }
}

// ---------------------------------------------------------------------------
// Fused GAT attention [R13-verified, unchanged]: block-local adjl/src_l,
// LDS hT staging, single-pass no-max softmax, ks-outer PV, swizzle, setprio.
// MODE 0: bx = ((b*2+head)*2+sub), sub {0,1}: tiles 0..6 / 7..12. F=32.
// MODE 1: bx = b*4+sub, sub {0..3}: tiles {0-3,4-6,7-9,10-12}. F=64.
// ---------------------------------------------------------------------------
template<int F, int MODE>
__global__ __launch_bounds__(256) void attn_mfma(const ushort* __restrict__ HT,
                                                 const unsigned* __restrict__ adjb,
                                                 const float* __restrict__ sd,
                                                 float* __restrict__ out)
{
    constexpr int NROW = (MODE == 0) ? 112 : 64;     // max rows per block
    __shared__ __attribute__((aligned(16))) ushort hT[F][232];
    __shared__ __attribute__((aligned(16))) float src_l[NROW];
    __shared__ __attribute__((aligned(16))) float dst_l[224];
    __shared__ unsigned adjl[NROW][9];   // pad 9 -> conflict-free row reads

    const int tid = threadIdx.x;
    const int lane = tid & 63, w = tid >> 6;
    // XCD swizzle (1024 = 8 x 128, bijective relabeling)
    const int bx = ((blockIdx.x & 7) << 7) | (blockIdx.x >> 3);
    int b, hoff, outc0, head, tA, tB;
    if (MODE == 0) {
        b = bx >> 2; head = (bx >> 1) & 1; const int sub = bx & 1;
        hoff = head * 32; outc0 = head * 32;
        tA = sub ? 7 : 0; tB = sub ? 13 : 7;
    } else {
        b = bx >> 2; head = 0; const int sub = bx & 3;
        hoff = 0; outc0 = 64;
        tA = (sub == 0) ? 0 : 4 + (sub - 1) * 3;
        tB = (sub == 0) ? 4 : tA + 3;
    }
    const int r0 = tA * 16;                          // first row of this block

    // stage hT (coalesced short8)
    const ushort* hg = HT + ((size_t)b * 64 + hoff) * 224;
    for (int idx = tid; idx < F * 28; idx += 256) {
        const int f = idx / 28, c = idx % 28;
        *(short8*)&hT[f][c * 8] = *(const short8*)&hg[(size_t)f * 224 + c * 8];
    }
    // stage adj bitmasks for OWN rows only (rows >= 200 -> 0)
    for (int idx = tid; idx < NROW * 8; idx += 256) {
        const int il = idx >> 3, c = idx & 7;
        const int i = r0 + il;
        adjl[il][c] = (i < 200) ? adjb[i * 8 + c] : 0u;
    }
    // stage dst (all cols) / src (own rows only)
    if (tid < 224) {
        float s = 0.f, d = 0.f;
        if (tid < 200) {
            if (MODE == 0) {
                const float4 q4 = *(const float4*)&sd[(size_t)(b * 200 + tid) * 4];
                s = head ? q4.z : q4.x;
                d = head ? q4.w : q4.y;
            } else {
                const float2 q2 = *(const float2*)&sd[(size_t)(b * 200 + tid) * 2];
                s = q2.x; d = q2.y;
            }
        }
        dst_l[tid] = d;
        const int local = tid - r0;
        if (local >= 0 && local < NROW) src_l[local] = s;
    }
    __syncthreads();

    const int m = lane & 15, g = lane >> 4;

    for (int t = tA + w; t < tB; t += 4) {
        const int i0 = t * 16;
        const int il = i0 - r0 + m;                  // local row index
        const float si = src_l[il];

        f32x4 acc[F / 16];
        #pragma unroll
        for (int nt = 0; nt < F / 16; ++nt) acc[nt] = f32x4{0, 0, 0, 0};
        float sum = 0.f;

        #pragma unroll
        for (int ks = 0; ks < 7; ++ks) {
            const unsigned bits = (adjl[il][ks] >> (g * 8)) & 0xffu;
            const float4 d0 = *(const float4*)&dst_l[ks * 32 + g * 8];
            const float4 d1 = *(const float4*)&dst_l[ks * 32 + g * 8 + 4];
            const float dvv[8] = {d0.x, d0.y, d0.z, d0.w, d1.x, d1.y, d1.z, d1.w};
            short8 af;
            #pragma unroll
            for (int u = 0; u < 8; ++u) {
                float v = si + dvv[u];
                v = fmaxf(v, ALPHA_ * v);                       // leaky-relu
                const float e = ((bits >> u) & 1u) ? v : NEGINF;
                const float p = __expf(fminf(e, 80.f));
                sum += p;
                af[u] = (short)f2b(p);
            }
            __builtin_amdgcn_s_setprio(1);
            #pragma unroll
            for (int nt = 0; nt < F / 16; ++nt) {
                const short8 bf = *(const short8*)&hT[nt * 16 + m][ks * 32 + g * 8];
                acc[nt] = __builtin_amdgcn_mfma_f32_16x16x32_bf16(af, bf, acc[nt], 0, 0, 0);
            }
            __builtin_amdgcn_s_setprio(0);
        }

        sum += __shfl_xor(sum, 16, 64);
        sum += __shfl_xor(sum, 32, 64);
        const float inv = 1.f / sum;           // inverse for row i0+m
        float invr[4];
        #pragma unroll
        for (int r = 0; r < 4; ++r) invr[r] = __shfl(inv, g * 4 + r, 64);

        #pragma unroll
        for (int nt = 0; nt < F / 16; ++nt) {
            #pragma unroll
            for (int r = 0; r < 4; ++r) {
                const int ii = i0 + g * 4 + r;
                if (ii < 200) {
                    float vv = acc[nt][r] * invr[r];
                    vv = (vv > 0.f) ? vv : expm1f(vv);          // accurate ELU
                    out[((size_t)b * 200 + ii) * 128 + outc0 + nt * 16 + m] = vv;
                }
            }
        }
    }
}

extern "C" void kernel_launch(void* const* d_in, const int* in_sizes, int n_in,
                              void* d_out, int out_size, void* d_ws, size_t ws_size,
                              hipStream_t stream)
{
    const float* x   = (const float*)d_in[0];
    const int*   adj = (const int*)  d_in[1];
    const float* W10 = (const float*)d_in[2];
    const float* a10 = (const float*)d_in[3];
    const float* W11 = (const float*)d_in[4];
    const float* a11 = (const float*)d_in[5];
    const float* W2  = (const float*)d_in[6];
    const float* a2  = (const float*)d_in[7];
    float* out = (float*)d_out;

    char* ws = (char*)d_ws;
    ushort*   HT   = (ushort*)  ws;                  // 7,340,032 B
    ushort*   WT1  = (ushort*) (ws + 7340032);       //    40,960 B
    ushort*   WT2  = (ushort*) (ws + 7380992);       //     8,192 B
    unsigned* adjb = (unsigned*)(ws + 7389184);      //     6,400 B
    float*    AC1  = (float*)  (ws + 7395584);       //     1,024 B
    float*    sd1  = (float*)  (ws + 7396608);       //   819,200 B
    float*    sd2  = (float*)  (ws + 8215808);       //   409,600 B  (8.63 MB)

    prep_kernel<<<200, 256, 0, stream>>>(adj, W10, W11, W2, a10, a11,
                                         adjb, WT1, WT2, AC1, HT);
    gemm_mfma<320, 320, 4><<<800, 256, 0, stream>>>(x, WT1, AC1, HT, sd1);
    attn_mfma<32, 0><<<1024, 256, 0, stream>>>(HT, adjb, sd1, out);
    gemm_mfma<64, 128, 2><<<800, 256, 0, stream>>>(out, WT2, a2, HT, sd2);
    attn_mfma<64, 1><<<1024, 256, 0, stream>>>(HT, adjb, sd2, out);
}

// Round 16
// 73.332 us; speedup vs baseline: 1.1568x; 1.0067x over previous
//
#include <hip/hip_runtime.h>
#include <cmath>

typedef __attribute__((ext_vector_type(8))) short short8;
typedef __attribute__((ext_vector_type(4))) float f32x4;

#define ALPHA_ 0.2f
#define NEGINF (-9.0e15f)

__device__ __forceinline__ ushort f2b(float f) {
    union { float f; unsigned u; } v; v.f = f;
    unsigned r = v.u + 0x7fffu + ((v.u >> 16) & 1u);
    return (ushort)(r >> 16);
}

// ---------------------------------------------------------------------------
// prep (grid 200 x 256)  [R6-verified, unchanged]
// ---------------------------------------------------------------------------
__global__ __launch_bounds__(256) void prep_kernel(
    const int* __restrict__ adj, const float* __restrict__ W10,
    const float* __restrict__ W11, const float* __restrict__ W2,
    const float* __restrict__ a10, const float* __restrict__ a11,
    unsigned* __restrict__ adjb, ushort* __restrict__ WT1,
    ushort* __restrict__ WT2, float* __restrict__ AC1,
    ushort* __restrict__ HT)
{
    const int bx = blockIdx.x, tid = threadIdx.x;
    if (tid < 8) {
        unsigned mask = 0;
        for (int u = 0; u < 32; ++u) {
            const int j = tid * 32 + u;
            if (j < 200 && adj[bx * 200 + j] > 0) mask |= (1u << u);
        }
        adjb[bx * 8 + tid] = mask;
    }
    const int gidx = bx * 256 + tid;                 // 0..51199
    if (gidx < 64 * 320) {
        const int n = gidx / 320, k = gidx % 320;
        WT1[gidx] = f2b(n < 32 ? W10[k * 32 + n] : W11[k * 32 + (n - 32)]);
    }
    if (gidx < 64 * 64) {
        const int n = gidx >> 6, k = gidx & 63;
        WT2[gidx] = f2b(W2[k * 64 + n]);
    }
    if (gidx < 256) {                                // AC1
        const int q = gidx >> 6, f = gidx & 63;
        float v = 0.f;
        if (q == 0 && f < 32)  v = a10[f];
        if (q == 1 && f < 32)  v = a10[32 + f];
        if (q == 2 && f >= 32) v = a11[f - 32];
        if (q == 3 && f >= 32) v = a11[f];           // a11[32 + (f-32)]
        AC1[gidx] = v;
    }
    if (gidx < 256 * 64 * 3) {                       // HT pad zero (3 x uint4 per row)
        const int c = gidx % 3, bf = gidx / 3;
        uint4 z{0, 0, 0, 0};
        *(uint4*)&HT[(size_t)bf * 224 + 200 + c * 8] = z;
    }
}

// ---------------------------------------------------------------------------
// gemm + fused src/dst dots  [R15 structure: W^T in LDS, x-loads hoisted]
// ---------------------------------------------------------------------------
template<int K, int LDX, int NSD>
__global__ __launch_bounds__(256) void gemm_mfma(const float* __restrict__ X,
                                                 const ushort* __restrict__ WT,
                                                 const float* __restrict__ AC,
                                                 ushort* __restrict__ HT,
                                                 float* __restrict__ SD)
{
    constexpr int KP = K + 8;
    constexpr int NK = K / 32;
    __shared__ __attribute__((aligned(16))) ushort wt_lds[64][KP];
    __shared__ __attribute__((aligned(16))) float acl[NSD * 64];
    const int tid = threadIdx.x;
    const int lane = tid & 63, w = tid >> 6;
    const int m = lane & 15, g = lane >> 4;
    const int ko = g * 8;
    const size_t row = (size_t)blockIdx.x * 64 + w * 16 + m;

    // ---- issue ALL x loads first
    float4 xr[NK][2];
    #pragma unroll
    for (int kk = 0; kk < NK; ++kk) {
        xr[kk][0] = *(const float4*)&X[row * LDX + kk * 32 + ko];
        xr[kk][1] = *(const float4*)&X[row * LDX + kk * 32 + ko + 4];
    }

    // ---- stage W^T into LDS (overlaps with x loads in flight)
    constexpr int CH = 64 * (K / 8);
    for (int c = tid; c < CH; c += 256) {
        int n = c / (K / 8), kc = (c % (K / 8)) * 8;
        *(short8*)&wt_lds[n][kc] = *(const short8*)&WT[n * K + kc];
    }
    if (tid < NSD * 64) acl[tid] = AC[tid];
    __syncthreads();

    // ---- compute: register-resident x, LDS-resident W
    f32x4 acc[4] = {{0,0,0,0},{0,0,0,0},{0,0,0,0},{0,0,0,0}};
    #pragma unroll
    for (int kk = 0; kk < NK; ++kk) {
        const float4 x0 = xr[kk][0];
        const float4 x1 = xr[kk][1];
        short8 a;
        a[0] = (short)f2b(x0.x); a[1] = (short)f2b(x0.y);
        a[2] = (short)f2b(x0.z); a[3] = (short)f2b(x0.w);
        a[4] = (short)f2b(x1.x); a[5] = (short)f2b(x1.y);
        a[6] = (short)f2b(x1.z); a[7] = (short)f2b(x1.w);
        #pragma unroll
        for (int nt = 0; nt < 4; ++nt) {
            const short8 bfr = *(const short8*)&wt_lds[nt * 16 + m][kk * 32 + ko];
            acc[nt] = __builtin_amdgcn_mfma_f32_16x16x32_bf16(a, bfr, acc[nt], 0, 0, 0);
        }
    }

    const unsigned rb = (unsigned)blockIdx.x * 64 + w * 16 + g * 4;  // 4 | 200
    const unsigned bt = rb / 200u;
    const unsigned ir = rb - bt * 200u;
    #pragma unroll
    for (int nt = 0; nt < 4; ++nt) {
        uint2 pk;
        pk.x = (unsigned)f2b(acc[nt][0]) | ((unsigned)f2b(acc[nt][1]) << 16);
        pk.y = (unsigned)f2b(acc[nt][2]) | ((unsigned)f2b(acc[nt][3]) << 16);
        *(uint2*)&HT[((size_t)bt * 64 + nt * 16 + m) * 224 + ir] = pk;
    }

    float sdv[NSD][4];
    #pragma unroll
    for (int q = 0; q < NSD; ++q)
        #pragma unroll
        for (int r = 0; r < 4; ++r) {
            float s = 0.f;
            #pragma unroll
            for (int nt = 0; nt < 4; ++nt) s += acc[nt][r] * acl[q * 64 + nt * 16 + m];
            sdv[q][r] = s;
        }
    #pragma unroll
    for (int q = 0; q < NSD; ++q)
        #pragma unroll
        for (int r = 0; r < 4; ++r) {
            float s = sdv[q][r];
            s += __shfl_xor(s, 1, 64); s += __shfl_xor(s, 2, 64);
            s += __shfl_xor(s, 4, 64); s += __shfl_xor(s, 8, 64);
            sdv[q][r] = s;
        }
    if (m == 0) {
        #pragma unroll
        for (int r = 0; r < 4; ++r) {
            if (NSD == 4) {
                float4 o; o.x = sdv[0][r]; o.y = sdv[1][r];
                o.z = sdv[2][r]; o.w = sdv[3][r];
                *(float4*)&SD[(size_t)(rb + r) * 4] = o;
            } else {
                float2 o; o.x = sdv[0][r]; o.y = sdv[1][r];
                *(float2*)&SD[(size_t)(rb + r) * 2] = o;
            }
        }
    }
}

// ---------------------------------------------------------------------------
// Fused GAT attention [R13-verified core].  R16: MODE 0 re-gridded to 4 subs
// per (b,head) — grid 2048, <=1 tile per wave, NROW=64, LDS ~18 KB => 8
// blocks/CU (was 4).  MODE 1 unchanged (grid 1024).
// MODE 0: bx = (b*2+head)*4+sub, sub {0..3}: tiles {0-3},{4-6},{7-9},{10-12}.
// MODE 1: bx = b*4+sub,          sub {0..3}: same tile split. F=64.
// ---------------------------------------------------------------------------
template<int F, int MODE>
__global__ __launch_bounds__(256) void attn_mfma(const ushort* __restrict__ HT,
                                                 const unsigned* __restrict__ adjb,
                                                 const float* __restrict__ sd,
                                                 float* __restrict__ out)
{
    constexpr int NROW = 64;                         // max rows per block
    constexpr int SH = (MODE == 0) ? 8 : 7;          // swizzle shift (grid/8)
    __shared__ __attribute__((aligned(16))) ushort hT[F][232];
    __shared__ __attribute__((aligned(16))) float src_l[NROW];
    __shared__ __attribute__((aligned(16))) float dst_l[224];
    __shared__ unsigned adjl[NROW][9];   // pad 9 -> conflict-free row reads

    const int tid = threadIdx.x;
    const int lane = tid & 63, w = tid >> 6;
    // XCD swizzle (grid = 8 x 2^SH, bijective relabeling)
    const int bx = ((blockIdx.x & 7) << SH) | (blockIdx.x >> 3);
    int b, hoff, outc0, head, sub;
    if (MODE == 0) {
        b = bx >> 3; head = (bx >> 2) & 1; sub = bx & 3;
        hoff = head * 32; outc0 = head * 32;
    } else {
        b = bx >> 2; head = 0; sub = bx & 3;
        hoff = 0; outc0 = 64;
    }
    const int tA = (sub == 0) ? 0 : 4 + (sub - 1) * 3;
    const int tB = (sub == 0) ? 4 : tA + 3;
    const int r0 = tA * 16;                          // first row of this block

    // stage hT (coalesced short8)
    const ushort* hg = HT + ((size_t)b * 64 + hoff) * 224;
    for (int idx = tid; idx < F * 28; idx += 256) {
        const int f = idx / 28, c = idx % 28;
        *(short8*)&hT[f][c * 8] = *(const short8*)&hg[(size_t)f * 224 + c * 8];
    }
    // stage adj bitmasks for OWN rows only (rows >= 200 -> 0)
    for (int idx = tid; idx < NROW * 8; idx += 256) {
        const int il = idx >> 3, c = idx & 7;
        const int i = r0 + il;
        adjl[il][c] = (i < 200) ? adjb[i * 8 + c] : 0u;
    }
    // stage dst (all cols) / src (own rows only)
    if (tid < 224) {
        float s = 0.f, d = 0.f;
        if (tid < 200) {
            if (MODE == 0) {
                const float4 q4 = *(const float4*)&sd[(size_t)(b * 200 + tid) * 4];
                s = head ? q4.z : q4.x;
                d = head ? q4.w : q4.y;
            } else {
                const float2 q2 = *(const float2*)&sd[(size_t)(b * 200 + tid) * 2];
                s = q2.x; d = q2.y;
            }
        }
        dst_l[tid] = d;
        const int local = tid - r0;
        if (local >= 0 && local < NROW) src_l[local] = s;
    }
    __syncthreads();

    const int m = lane & 15, g = lane >> 4;

    for (int t = tA + w; t < tB; t += 4) {
        const int i0 = t * 16;
        const int il = i0 - r0 + m;                  // local row index
        const float si = src_l[il];

        f32x4 acc[F / 16];
        #pragma unroll
        for (int nt = 0; nt < F / 16; ++nt) acc[nt] = f32x4{0, 0, 0, 0};
        float sum = 0.f;

        #pragma unroll
        for (int ks = 0; ks < 7; ++ks) {
            const unsigned bits = (adjl[il][ks] >> (g * 8)) & 0xffu;
            const float4 d0 = *(const float4*)&dst_l[ks * 32 + g * 8];
            const float4 d1 = *(const float4*)&dst_l[ks * 32 + g * 8 + 4];
            const float dvv[8] = {d0.x, d0.y, d0.z, d0.w, d1.x, d1.y, d1.z, d1.w};
            short8 af;
            #pragma unroll
            for (int u = 0; u < 8; ++u) {
                float v = si + dvv[u];
                v = fmaxf(v, ALPHA_ * v);                       // leaky-relu
                const float e = ((bits >> u) & 1u) ? v : NEGINF;
                const float p = __expf(fminf(e, 80.f));
                sum += p;
                af[u] = (short)f2b(p);
            }
            __builtin_amdgcn_s_setprio(1);
            #pragma unroll
            for (int nt = 0; nt < F / 16; ++nt) {
                const short8 bf = *(const short8*)&hT[nt * 16 + m][ks * 32 + g * 8];
                acc[nt] = __builtin_amdgcn_mfma_f32_16x16x32_bf16(af, bf, acc[nt], 0, 0, 0);
            }
            __builtin_amdgcn_s_setprio(0);
        }

        sum += __shfl_xor(sum, 16, 64);
        sum += __shfl_xor(sum, 32, 64);
        const float inv = 1.f / sum;           // inverse for row i0+m
        float invr[4];
        #pragma unroll
        for (int r = 0; r < 4; ++r) invr[r] = __shfl(inv, g * 4 + r, 64);

        #pragma unroll
        for (int nt = 0; nt < F / 16; ++nt) {
            #pragma unroll
            for (int r = 0; r < 4; ++r) {
                const int ii = i0 + g * 4 + r;
                if (ii < 200) {
                    float vv = acc[nt][r] * invr[r];
                    vv = (vv > 0.f) ? vv : expm1f(vv);          // accurate ELU
                    out[((size_t)b * 200 + ii) * 128 + outc0 + nt * 16 + m] = vv;
                }
            }
        }
    }
}

extern "C" void kernel_launch(void* const* d_in, const int* in_sizes, int n_in,
                              void* d_out, int out_size, void* d_ws, size_t ws_size,
                              hipStream_t stream)
{
    const float* x   = (const float*)d_in[0];
    const int*   adj = (const int*)  d_in[1];
    const float* W10 = (const float*)d_in[2];
    const float* a10 = (const float*)d_in[3];
    const float* W11 = (const float*)d_in[4];
    const float* a11 = (const float*)d_in[5];
    const float* W2  = (const float*)d_in[6];
    const float* a2  = (const float*)d_in[7];
    float* out = (float*)d_out;

    char* ws = (char*)d_ws;
    ushort*   HT   = (ushort*)  ws;                  // 7,340,032 B
    ushort*   WT1  = (ushort*) (ws + 7340032);       //    40,960 B
    ushort*   WT2  = (ushort*) (ws + 7380992);       //     8,192 B
    unsigned* adjb = (unsigned*)(ws + 7389184);      //     6,400 B
    float*    AC1  = (float*)  (ws + 7395584);       //     1,024 B
    float*    sd1  = (float*)  (ws + 7396608);       //   819,200 B
    float*    sd2  = (float*)  (ws + 8215808);       //   409,600 B  (8.63 MB)

    prep_kernel<<<200, 256, 0, stream>>>(adj, W10, W11, W2, a10, a11,
                                         adjb, WT1, WT2, AC1, HT);
    gemm_mfma<320, 320, 4><<<800, 256, 0, stream>>>(x, WT1, AC1, HT, sd1);
    attn_mfma<32, 0><<<2048, 256, 0, stream>>>(HT, adjb, sd1, out);
    gemm_mfma<64, 128, 2><<<800, 256, 0, stream>>>(out, WT2, a2, HT, sd2);
    attn_mfma<64, 1><<<1024, 256, 0, stream>>>(HT, adjb, sd2, out);
}